// Round 10
// baseline (937.695 us; speedup 1.0000x reference)
//
#include <hip/hip_runtime.h>

#define DEVINL __device__ __forceinline__

// Exact (no-FMA-contraction) squared distance in the same rounding order as
// numpy/jax fp32: ((dx*dx + dy*dy) + dz*dz). Discrete decisions (FPS argmax,
// ball-query radius compare) depend on bit-exactness.
DEVINL float sq3(float ax, float ay, float az, float bx, float by, float bz) {
  float dx = __fsub_rn(ax, bx), dy = __fsub_rn(ay, by), dz = __fsub_rn(az, bz);
  return __fadd_rn(__fadd_rn(__fmul_rn(dx, dx), __fmul_rn(dy, dy)), __fmul_rn(dz, dz));
}

// DPP max-trees (VALU pipe). old=own so invalid-lane results are identity-safe
// for max. row_shr:1/2/4/8 + row_bcast:15 (+ row_bcast:31) -> 32/64-lane max;
// 64-lane result valid at lane 63 (proven rounds 4-9, absmax 0.0).
template <int CTRL>
DEVINL float dpp_maxf(float v) {
  int o = __builtin_amdgcn_update_dpp(__float_as_int(v), __float_as_int(v),
                                      CTRL, 0xf, 0xf, false);
  return fmaxf(v, __int_as_float(o));
}
DEVINL float red32_maxf(float v) {  // 32-lane group max -> valid at lanes 31,63
  v = dpp_maxf<0x111>(v); v = dpp_maxf<0x112>(v); v = dpp_maxf<0x114>(v);
  v = dpp_maxf<0x118>(v); v = dpp_maxf<0x142>(v);
  return v;
}
DEVINL float red64_maxf(float v) {  // 64-lane max -> valid at lane 63
  v = red32_maxf(v); v = dpp_maxf<0x143>(v);
  return v;
}
// u64 packed-key max tree: both halves move with the same DPP ctrl (pair stays
// consistent: both read the same source lane). Valid at lane 63 after 6 levels.
template <int CTRL>
DEVINL unsigned long long dpp_maxk(unsigned long long k) {
  const unsigned lo = (unsigned)k, hi = (unsigned)(k >> 32);
  const unsigned olo = (unsigned)__builtin_amdgcn_update_dpp(
      (int)lo, (int)lo, CTRL, 0xf, 0xf, false);
  const unsigned ohi = (unsigned)__builtin_amdgcn_update_dpp(
      (int)hi, (int)hi, CTRL, 0xf, 0xf, false);
  const unsigned long long ok = ((unsigned long long)ohi << 32) | olo;
  return (ok > k) ? ok : k;
}
DEVINL unsigned long long red64_maxk(unsigned long long k) {
  k = dpp_maxk<0x111>(k); k = dpp_maxk<0x112>(k); k = dpp_maxk<0x114>(k);
  k = dpp_maxk<0x118>(k); k = dpp_maxk<0x142>(k); k = dpp_maxk<0x143>(k);
  return k;
}

// ---------------------------------------------------------------------------
// K1: farthest point sampling — EXACT round-6 config (measured 244 us; rounds
// 7 (8 waves) and 9 (1 wave) both regressed: the ~1150 cy/step chain is the
// empirical optimum at 4 waves x 8 pts with coord-carry). One block per
// batch, 256 threads, packed-u64 DPP tree (val<<32 | 2047-idx: u64 max ==
// first-occurrence argmax), lane 63 publishes (key, winner coords), one
// barrier, every thread combines 4 pairs. Parity double-buffered.
// ---------------------------------------------------------------------------
__global__ __launch_bounds__(256) void k_fps(const float* __restrict__ xyz,
                                             int* __restrict__ fidx) {
  const int b = blockIdx.x, t = threadIdx.x;
  __shared__ float xs[2048], ys[2048], zs[2048];
  __shared__ unsigned long long skey[2][4];
  __shared__ float4 scoord[2][4];
  const float* P = xyz + (size_t)b * 6144;
  for (int i = t; i < 2048; i += 256) {
    xs[i] = P[3 * i]; ys[i] = P[3 * i + 1]; zs[i] = P[3 * i + 2];
  }
  __syncthreads();
  float px[8], py[8], pz[8], dist[8];
#pragma unroll
  for (int j = 0; j < 8; ++j) {
    const int idx = j * 256 + t;
    px[j] = xs[idx]; py[j] = ys[idx]; pz[j] = zs[idx];
    dist[j] = 1e10f;
  }
  int far = 0;
  float cx = xs[0], cy = ys[0], cz = zs[0];
  int* out = fidx + b * 512;
  for (int it = 0; it < 512; ++it) {
    if (t == 0) out[it] = far;  // emit BEFORE update (scan emits carry's far)
    float bv = -1.0f;
    int bi = 0;
#pragma unroll
    for (int j = 0; j < 8; ++j) {
      const float d = sq3(px[j], py[j], pz[j], cx, cy, cz);
      const float nd = fminf(dist[j], d);
      dist[j] = nd;
      if (nd > bv) { bv = nd; bi = j * 256 + t; }  // strict >: smallest idx kept
    }
    // packed key: larger value wins; tie -> larger (2047-idx) -> smaller idx
    unsigned long long key =
        ((unsigned long long)__float_as_uint(bv) << 32) | (unsigned)(2047 - bi);
    key = red64_maxk(key);  // wave winner at lane 63
    const int par = it & 1;
    if ((t & 63) == 63) {
      const int widx = 2047 - (int)((unsigned)key & 2047u);
      skey[par][t >> 6] = key;
      scoord[par][t >> 6] = make_float4(xs[widx], ys[widx], zs[widx], 0.0f);
    }
    __syncthreads();
    unsigned long long k0 = skey[par][0], k1 = skey[par][1];
    unsigned long long k2 = skey[par][2], k3 = skey[par][3];
    float4 c0 = scoord[par][0], c1 = scoord[par][1];
    float4 c2 = scoord[par][2], c3 = scoord[par][3];
    if (k1 > k0) { k0 = k1; c0 = c1; }
    if (k3 > k2) { k2 = k3; c2 = c3; }
    if (k2 > k0) { k0 = k2; c0 = c2; }
    far = 2047 - (int)((unsigned)k0 & 2047u);
    cx = c0.x; cy = c0.y; cz = c0.z;
  }
}

// ---------------------------------------------------------------------------
// K2: ball query + worklist emission. One wave per centroid. Collect first 32
// ascending in-radius indices (staged in LDS) and append the DISTINCT items
// to a global worklist as (g<<11 | srcidx). Rationale: radius 0.2 on N(0,1)
// points -> E[hits] ~ 1-3, so the reference's padding duplicates ~90% of
// sa1's sample evaluations; max over duplicates == max over distinct (EXACT).
// Every group has >= 1 hit (its own centroid, d2 = 0 <= r2).
// ---------------------------------------------------------------------------
__global__ __launch_bounds__(256) void k_ballq(const float* __restrict__ xyz,
                                               const int* __restrict__ fidx,
                                               float* __restrict__ new_xyz,
                                               unsigned* __restrict__ wlist,
                                               unsigned* __restrict__ wcount) {
  const int gw = (blockIdx.x * 256 + threadIdx.x) >> 6;  // centroid id
  const int wv = (threadIdx.x >> 6);                     // wave within block
  const int lane = threadIdx.x & 63;
  const int b = gw >> 9;
  __shared__ int stage[4][32];
  const float* P = xyz + (size_t)b * 6144;
  const int cidx = fidx[gw];
  const float cx = P[3 * cidx], cy = P[3 * cidx + 1], cz = P[3 * cidx + 2];
  if (lane < 3) new_xyz[(size_t)gw * 3 + lane] = P[3 * cidx + lane];
  int base = 0;
  for (int c0 = 0; c0 < 2048; c0 += 64) {
    const int idx = c0 + lane;
    const float d = sq3(cx, cy, cz, P[3 * idx], P[3 * idx + 1], P[3 * idx + 2]);
    const bool in = !(d > 0.04f);  // matches: exclude where sqr > r*r
    const unsigned long long m = __ballot(in);
    if (in) {
      const int pos = base + (int)__popcll(m & ((1ull << lane) - 1ull));
      if (pos < 32) stage[wv][pos] = idx;
    }
    base += (int)__popcll(m);
    if (base >= 32) break;  // wave-uniform
  }
  __syncthreads();  // stage[] visible (all threads reach; break is uniform)
  const int n = (base < 32) ? base : 32;
  unsigned off = 0;
  if (lane == 0) off = atomicAdd(wcount, (unsigned)n);
  off = (unsigned)__shfl((int)off, 0);
  if (lane < n)
    wlist[off + lane] = ((unsigned)gw << 11) | (unsigned)stage[wv][lane];
}

// ---------------------------------------------------------------------------
// K3: SA1 over distinct worklist items only. Grid-stride over W (read from
// device counter -> correct for any input; ~33k items expected vs 524k).
// Per item: MLP 3->64->64 (sv structure, r4-proven), relu, then 128 outputs
// combined into l1p via atomicMax on uint-viewed floats (all values >= 0 and
// l1p zero-initialized, so uint order == float order: EXACT max).
// ---------------------------------------------------------------------------
__global__ __launch_bounds__(256, 2) void k_sa1i(
    const float* __restrict__ xyz, const float* __restrict__ new_xyz,
    const unsigned* __restrict__ wlist, const unsigned* __restrict__ wcount,
    const float* __restrict__ w0, const float* __restrict__ b0,
    const float* __restrict__ w1, const float* __restrict__ b1,
    const float* __restrict__ w2, const float* __restrict__ b2,
    unsigned* __restrict__ l1pu) {
  const unsigned W = *wcount;
  for (unsigned i = blockIdx.x * 256 + threadIdx.x; i < W;
       i += gridDim.x * 256) {
    const unsigned item = wlist[i];
    const int g = (int)(item >> 11);
    const int src = (int)(item & 2047u);
    const int b = g >> 9;
    const float* P = xyz + (size_t)b * 6144;
    const float nx = new_xyz[(size_t)g * 3], ny = new_xyz[(size_t)g * 3 + 1],
                nz = new_xyz[(size_t)g * 3 + 2];
    const float x = P[3 * src] - nx, y = P[3 * src + 1] - ny,
                z = P[3 * src + 2] - nz;
    float sv[64];
#pragma unroll
    for (int d = 0; d < 64; ++d) sv[d] = b1[d];
#pragma unroll
    for (int half = 0; half < 2; ++half) {
      float h0[32];
#pragma unroll
      for (int d = 0; d < 32; ++d) {
        const int dd = half * 32 + d;
        h0[d] = fmaxf(0.0f, fmaf(w0[3 * dd], x,
                                 fmaf(w0[3 * dd + 1], y,
                                      fmaf(w0[3 * dd + 2], z, b0[dd]))));
      }
#pragma unroll
      for (int d1 = 0; d1 < 64; ++d1) {
        const float* wr = w1 + (d1 << 6) + half * 32;
        float s0 = 0.f, s1 = 0.f, s2 = 0.f, s3 = 0.f;
#pragma unroll
        for (int c = 0; c < 32; c += 4) {
          s0 = fmaf(wr[c], h0[c], s0);
          s1 = fmaf(wr[c + 1], h0[c + 1], s1);
          s2 = fmaf(wr[c + 2], h0[c + 2], s2);
          s3 = fmaf(wr[c + 3], h0[c + 3], s3);
        }
        sv[d1] += (s0 + s1) + (s2 + s3);
      }
    }
#pragma unroll
    for (int d = 0; d < 64; ++d) sv[d] = fmaxf(0.0f, sv[d]);
    unsigned* outg = l1pu + (size_t)g * 128;
    for (int e = 0; e < 128; ++e) {
      const float* wr = w2 + (e << 6);
      float s0 = 0.f, s1 = 0.f, s2 = 0.f, s3 = 0.f;
#pragma unroll
      for (int c = 0; c < 64; c += 4) {
        s0 = fmaf(wr[c], sv[c], s0);
        s1 = fmaf(wr[c + 1], sv[c + 1], s1);
        s2 = fmaf(wr[c + 2], sv[c + 2], s2);
        s3 = fmaf(wr[c + 3], sv[c + 3], s3);
      }
      const float v = fmaxf(0.0f, b2[e] + ((s0 + s1) + (s2 + s3)));
      atomicMax(outg + e, __float_as_uint(v));
    }
  }
}

// ---------------------------------------------------------------------------
// SA2 layer kernels: lane = point (m), A row in registers (float4 packed
// [d/4][m][4] intermediates), weights via wave-uniform scalar path.
// 16-dim chunks for 2-4 blocks/CU latency hiding (round-6 win).
// ---------------------------------------------------------------------------
__global__ __launch_bounds__(256, 2) void k_sa2_l0(
    const float* __restrict__ new_xyz, const float* __restrict__ l1p,
    const float* __restrict__ w0, const float* __restrict__ b0,
    float4* __restrict__ h0t4) {
  const int pb = blockIdx.x >> 3, ds = blockIdx.x & 7;  // 8 chunks x 16 dims
  const int t = threadIdx.x;
  const int d0 = ds * 16;
  const int m = pb * 256 + t;
  const float ax = new_xyz[(size_t)m * 3], ay = new_xyz[(size_t)m * 3 + 1],
              az = new_xyz[(size_t)m * 3 + 2];
  float4 av[32];
  const float4* lp = (const float4*)(l1p + (size_t)m * 128);
#pragma unroll
  for (int i = 0; i < 32; ++i) av[i] = lp[i];
  for (int dq = 0; dq < 4; ++dq) {
    float o[4];
#pragma unroll
    for (int k = 0; k < 4; ++k) {
      const int dd = 4 * dq + k;
      const float* wr = w0 + (size_t)(d0 + dd) * 131;
      float s = fmaf(wr[0], ax, fmaf(wr[1], ay, fmaf(wr[2], az, b0[d0 + dd])));
      float s0 = 0.f, s1 = 0.f, s2 = 0.f, s3 = 0.f;
#pragma unroll
      for (int i = 0; i < 32; ++i) {
        s0 = fmaf(wr[3 + 4 * i], av[i].x, s0);
        s1 = fmaf(wr[4 + 4 * i], av[i].y, s1);
        s2 = fmaf(wr[5 + 4 * i], av[i].z, s2);
        s3 = fmaf(wr[6 + 4 * i], av[i].w, s3);
      }
      o[k] = fmaxf(0.0f, s + ((s0 + s1) + (s2 + s3)));
    }
    h0t4[(size_t)(ds * 4 + dq) * 16384 + m] =
        make_float4(o[0], o[1], o[2], o[3]);
  }
}

__global__ __launch_bounds__(256, 2) void k_sa2_l1(
    const float4* __restrict__ h0t4, const float* __restrict__ w1,
    const float* __restrict__ b1, float4* __restrict__ h1t4) {
  const int pb = blockIdx.x >> 3, ds = blockIdx.x & 7;  // 8 chunks x 16 dims
  const int t = threadIdx.x;
  const int d0 = ds * 16;
  const int m = pb * 256 + t;
  float4 a4[32];
#pragma unroll
  for (int i = 0; i < 32; ++i) a4[i] = h0t4[(size_t)i * 16384 + m];
  for (int dq = 0; dq < 4; ++dq) {
    float o[4];
#pragma unroll
    for (int k = 0; k < 4; ++k) {
      const int dd = 4 * dq + k;
      const float* wr = w1 + (size_t)(d0 + dd) * 128;
      float s0 = 0.f, s1 = 0.f, s2 = 0.f, s3 = 0.f;
#pragma unroll
      for (int i = 0; i < 32; ++i) {
        s0 = fmaf(wr[4 * i], a4[i].x, s0);
        s1 = fmaf(wr[4 * i + 1], a4[i].y, s1);
        s2 = fmaf(wr[4 * i + 2], a4[i].z, s2);
        s3 = fmaf(wr[4 * i + 3], a4[i].w, s3);
      }
      o[k] = fmaxf(0.0f, b1[d0 + dd] + ((s0 + s1) + (s2 + s3)));
    }
    h1t4[(size_t)(ds * 4 + dq) * 16384 + m] =
        make_float4(o[0], o[1], o[2], o[3]);
  }
}

__global__ __launch_bounds__(256, 2) void k_sa2_l2max(
    const float4* __restrict__ h1t4, const float* __restrict__ w2,
    const float* __restrict__ b2, float* __restrict__ pmax) {
  const int pb = blockIdx.x >> 4, ds = blockIdx.x & 15;  // 16 chunks x 16 dims
  const int t = threadIdx.x;
  const int d0 = ds * 16;
  const int m = pb * 256 + t;
  const int b = m >> 9;
  const int wc = ((pb << 2) + (t >> 6)) & 7;  // wave-chunk within batch (0..7)
  float4 a4[32];
#pragma unroll
  for (int i = 0; i < 32; ++i) a4[i] = h1t4[(size_t)i * 16384 + m];
  for (int dq = 0; dq < 4; ++dq) {
#pragma unroll
    for (int k = 0; k < 4; ++k) {
      const int dd = 4 * dq + k;
      const float* wr = w2 + (size_t)(d0 + dd) * 128;
      float s0 = 0.f, s1 = 0.f, s2 = 0.f, s3 = 0.f;
#pragma unroll
      for (int i = 0; i < 32; ++i) {
        s0 = fmaf(wr[4 * i], a4[i].x, s0);
        s1 = fmaf(wr[4 * i + 1], a4[i].y, s1);
        s2 = fmaf(wr[4 * i + 2], a4[i].z, s2);
        s3 = fmaf(wr[4 * i + 3], a4[i].w, s3);
      }
      float v = fmaxf(0.0f, b2[d0 + dd] + ((s0 + s1) + (s2 + s3)));
      v = red64_maxf(v);  // wave max, valid at lane 63
      if ((t & 63) == 63) pmax[((size_t)(b << 3) + wc) * 256 + d0 + dd] = v;
    }
  }
}

// ---------------------------------------------------------------------------
// K7: head. One block (1 wave) per batch. obj = max over 8 wave-partials,
// pose MLP + fusion MLP + two scalar heads.
// ---------------------------------------------------------------------------
__global__ __launch_bounds__(64) void k_head(
    const float* __restrict__ pmax, const float* __restrict__ grasp,
    const float* __restrict__ initp, const float* __restrict__ finalp,
    const int* __restrict__ surf, const float* __restrict__ embi,
    const float* __restrict__ embf, const float* __restrict__ pw0,
    const float* __restrict__ pb0, const float* __restrict__ pw1,
    const float* __restrict__ pb1, const float* __restrict__ pw2,
    const float* __restrict__ pb2, const float* __restrict__ fw0,
    const float* __restrict__ fb0, const float* __restrict__ fw1,
    const float* __restrict__ fb1, const float* __restrict__ osw,
    const float* __restrict__ osb, const float* __restrict__ ocw,
    const float* __restrict__ ocb, float* __restrict__ out) {
  __shared__ float obj[256], xb[37], A0[64], A1[128], A2[128], F0[128], HID[64];
  const int b = blockIdx.x, l = threadIdx.x;
  const float* pm = pmax + (size_t)b * 2048;
  for (int e = l; e < 256; e += 64) {
    float v = pm[e];
#pragma unroll
    for (int w = 1; w < 8; ++w) v = fmaxf(v, pm[w * 256 + e]);
    obj[e] = v;
  }
  if (l < 7) xb[l] = grasp[b * 7 + l];
  else if (l < 14) xb[l] = initp[b * 7 + l - 7];
  else if (l < 21) xb[l] = finalp[b * 7 + l - 14];
  else if (l < 29) xb[l] = embi[surf[b * 2] * 8 + l - 21];
  else if (l < 37) xb[l] = embf[surf[b * 2 + 1] * 8 + l - 29];
  __syncthreads();
  {
    float s = pb0[l];
    const float* wr = pw0 + l * 37;
#pragma unroll
    for (int c = 0; c < 37; ++c) s = fmaf(xb[c], wr[c], s);
    A0[l] = fmaxf(0.f, s);
  }
  __syncthreads();
#pragma unroll
  for (int dd = 0; dd < 2; ++dd) {
    const int d = l + dd * 64;
    float s = pb1[d];
    const float* wr = pw1 + d * 64;
#pragma unroll
    for (int c = 0; c < 64; ++c) s = fmaf(A0[c], wr[c], s);
    A1[d] = fmaxf(0.f, s);
  }
  __syncthreads();
#pragma unroll
  for (int dd = 0; dd < 2; ++dd) {
    const int d = l + dd * 64;
    float s = pb2[d];
    const float* wr = pw2 + d * 128;
#pragma unroll 16
    for (int c = 0; c < 128; ++c) s = fmaf(A1[c], wr[c], s);
    A2[d] = fmaxf(0.f, s);
  }
  __syncthreads();
#pragma unroll
  for (int dd = 0; dd < 2; ++dd) {
    const int d = l + dd * 64;
    float s = fb0[d];
    const float* wr = fw0 + d * 384;
#pragma unroll 16
    for (int c = 0; c < 256; ++c) s = fmaf(obj[c], wr[c], s);
#pragma unroll 16
    for (int c = 0; c < 128; ++c) s = fmaf(A2[c], wr[256 + c], s);
    F0[d] = fmaxf(0.f, s);
  }
  __syncthreads();
  {
    float s = fb1[l];
    const float* wr = fw1 + l * 128;
#pragma unroll 16
    for (int c = 0; c < 128; ++c) s = fmaf(F0[c], wr[c], s);
    HID[l] = fmaxf(0.f, s);
  }
  __syncthreads();
  float v1 = HID[l] * osw[l];
  float v2 = HID[l] * ocw[l];
#pragma unroll
  for (int off = 1; off < 64; off <<= 1) {
    v1 += __shfl_xor(v1, off);
    v2 += __shfl_xor(v2, off);
  }
  if (l == 0) {
    out[b] = v1 + osb[0];
    out[32 + b] = v2 + ocb[0];
  }
}

extern "C" void kernel_launch(void* const* d_in, const int* in_sizes, int n_in,
                              void* d_out, int out_size, void* d_ws, size_t ws_size,
                              hipStream_t stream) {
  const float* points  = (const float*)d_in[0];
  const float* grasp   = (const float*)d_in[1];
  const float* initp   = (const float*)d_in[2];
  const float* finalp  = (const float*)d_in[3];
  const int*   surf    = (const int*)d_in[4];
  const float* sa1_w0  = (const float*)d_in[5];
  const float* sa1_b0  = (const float*)d_in[6];
  const float* sa1_w1  = (const float*)d_in[7];
  const float* sa1_b1  = (const float*)d_in[8];
  const float* sa1_w2  = (const float*)d_in[9];
  const float* sa1_b2  = (const float*)d_in[10];
  const float* sa2_w0  = (const float*)d_in[11];
  const float* sa2_b0  = (const float*)d_in[12];
  const float* sa2_w1  = (const float*)d_in[13];
  const float* sa2_b1  = (const float*)d_in[14];
  const float* sa2_w2  = (const float*)d_in[15];
  const float* sa2_b2  = (const float*)d_in[16];
  const float* embi    = (const float*)d_in[17];
  const float* embf    = (const float*)d_in[18];
  const float* pe_w0   = (const float*)d_in[19];
  const float* pe_b0   = (const float*)d_in[20];
  const float* pe_w1   = (const float*)d_in[21];
  const float* pe_b1   = (const float*)d_in[22];
  const float* pe_w2   = (const float*)d_in[23];
  const float* pe_b2   = (const float*)d_in[24];
  const float* fu_w0   = (const float*)d_in[25];
  const float* fu_b0   = (const float*)d_in[26];
  const float* fu_w1   = (const float*)d_in[27];
  const float* fu_b1   = (const float*)d_in[28];
  const float* os_w    = (const float*)d_in[29];
  const float* os_b    = (const float*)d_in[30];
  const float* oc_w    = (const float*)d_in[31];
  const float* oc_b    = (const float*)d_in[32];

  char* ws = (char*)d_ws;
  // layout (bytes):
  int*      fidx    = (int*)(ws + 0);            //  65536
  float*    new_xyz = (float*)(ws + 65536);      // 196608
  unsigned* wlist   = (unsigned*)(ws + 262144);  // 2097152 (max 524288 items)
  float*    l1p     = (float*)(ws + 2359296);    // 8388608 (reused as h1t)
  float4*   h0t4    = (float4*)(ws + 10747904);  // 8388608
  float*    pmax    = (float*)(ws + 19136512);   // 262144  -> end 19398656
  unsigned* wcount  = (unsigned*)(ws + 19398656);  // 4
  float4*   h1t4    = (float4*)l1p;  // l1_points dead after k_sa2_l0

  float* out = (float*)d_out;

  // Per-call zero-init (harness does not re-poison between replays):
  hipMemsetAsync(l1p, 0, 16384 * 128 * sizeof(float), stream);
  hipMemsetAsync(wcount, 0, sizeof(unsigned), stream);

  k_fps<<<32, 256, 0, stream>>>(points, fidx);
  k_ballq<<<4096, 256, 0, stream>>>(points, fidx, new_xyz, wlist, wcount);
  k_sa1i<<<256, 256, 0, stream>>>(points, new_xyz, wlist, wcount, sa1_w0,
                                  sa1_b0, sa1_w1, sa1_b1, sa1_w2, sa1_b2,
                                  (unsigned*)l1p);
  k_sa2_l0<<<512, 256, 0, stream>>>(new_xyz, l1p, sa2_w0, sa2_b0, h0t4);
  k_sa2_l1<<<512, 256, 0, stream>>>(h0t4, sa2_w1, sa2_b1, h1t4);
  k_sa2_l2max<<<1024, 256, 0, stream>>>(h1t4, sa2_w2, sa2_b2, pmax);
  k_head<<<32, 64, 0, stream>>>(pmax, grasp, initp, finalp, surf, embi, embf,
                                pe_w0, pe_b0, pe_w1, pe_b1, pe_w2, pe_b2, fu_w0,
                                fu_b0, fu_w1, fu_b1, os_w, os_b, oc_w, oc_b, out);
}

// Round 11
// 506.391 us; speedup vs baseline: 1.8517x; 1.8517x over previous
//
#include <hip/hip_runtime.h>

#define DEVINL __device__ __forceinline__

// Exact (no-FMA-contraction) squared distance in the same rounding order as
// numpy/jax fp32: ((dx*dx + dy*dy) + dz*dz). Discrete decisions (FPS argmax,
// ball-query radius compare) depend on bit-exactness.
DEVINL float sq3(float ax, float ay, float az, float bx, float by, float bz) {
  float dx = __fsub_rn(ax, bx), dy = __fsub_rn(ay, by), dz = __fsub_rn(az, bz);
  return __fadd_rn(__fadd_rn(__fmul_rn(dx, dx), __fmul_rn(dy, dy)), __fmul_rn(dz, dz));
}

DEVINL float rdlane(float v, int l) {  // l compile-time const in unrolled loops
  return __int_as_float(__builtin_amdgcn_readlane(__float_as_int(v), l));
}

// DPP max-trees (VALU pipe). old=own so invalid-lane results are identity-safe
// for max. row_shr:1/2/4/8 + row_bcast:15 (+ row_bcast:31) -> 32/64-lane max;
// 64-lane result valid at lane 63 (proven rounds 4-10, absmax 0.0).
template <int CTRL>
DEVINL float dpp_maxf(float v) {
  int o = __builtin_amdgcn_update_dpp(__float_as_int(v), __float_as_int(v),
                                      CTRL, 0xf, 0xf, false);
  return fmaxf(v, __int_as_float(o));
}
DEVINL float red32_maxf(float v) {
  v = dpp_maxf<0x111>(v); v = dpp_maxf<0x112>(v); v = dpp_maxf<0x114>(v);
  v = dpp_maxf<0x118>(v); v = dpp_maxf<0x142>(v);
  return v;
}
DEVINL float red64_maxf(float v) {
  v = red32_maxf(v); v = dpp_maxf<0x143>(v);
  return v;
}
template <int CTRL>
DEVINL unsigned long long dpp_maxk(unsigned long long k) {
  const unsigned lo = (unsigned)k, hi = (unsigned)(k >> 32);
  const unsigned olo = (unsigned)__builtin_amdgcn_update_dpp(
      (int)lo, (int)lo, CTRL, 0xf, 0xf, false);
  const unsigned ohi = (unsigned)__builtin_amdgcn_update_dpp(
      (int)hi, (int)hi, CTRL, 0xf, 0xf, false);
  const unsigned long long ok = ((unsigned long long)ohi << 32) | olo;
  return (ok > k) ? ok : k;
}
DEVINL unsigned long long red64_maxk(unsigned long long k) {
  k = dpp_maxk<0x111>(k); k = dpp_maxk<0x112>(k); k = dpp_maxk<0x114>(k);
  k = dpp_maxk<0x118>(k); k = dpp_maxk<0x142>(k); k = dpp_maxk<0x143>(k);
  return k;
}

// ---------------------------------------------------------------------------
// K1: farthest point sampling — EXACT round-6 config (measured 244 us; 8-wave
// and 1-wave variants both regressed; ~1150 cy/step chain is the empirical
// optimum at 4 waves x 8 pts with coord-carry).
// ---------------------------------------------------------------------------
__global__ __launch_bounds__(256) void k_fps(const float* __restrict__ xyz,
                                             int* __restrict__ fidx) {
  const int b = blockIdx.x, t = threadIdx.x;
  __shared__ float xs[2048], ys[2048], zs[2048];
  __shared__ unsigned long long skey[2][4];
  __shared__ float4 scoord[2][4];
  const float* P = xyz + (size_t)b * 6144;
  for (int i = t; i < 2048; i += 256) {
    xs[i] = P[3 * i]; ys[i] = P[3 * i + 1]; zs[i] = P[3 * i + 2];
  }
  __syncthreads();
  float px[8], py[8], pz[8], dist[8];
#pragma unroll
  for (int j = 0; j < 8; ++j) {
    const int idx = j * 256 + t;
    px[j] = xs[idx]; py[j] = ys[idx]; pz[j] = zs[idx];
    dist[j] = 1e10f;
  }
  int far = 0;
  float cx = xs[0], cy = ys[0], cz = zs[0];
  int* out = fidx + b * 512;
  for (int it = 0; it < 512; ++it) {
    if (t == 0) out[it] = far;  // emit BEFORE update (scan emits carry's far)
    float bv = -1.0f;
    int bi = 0;
#pragma unroll
    for (int j = 0; j < 8; ++j) {
      const float d = sq3(px[j], py[j], pz[j], cx, cy, cz);
      const float nd = fminf(dist[j], d);
      dist[j] = nd;
      if (nd > bv) { bv = nd; bi = j * 256 + t; }  // strict >: smallest idx kept
    }
    unsigned long long key =
        ((unsigned long long)__float_as_uint(bv) << 32) | (unsigned)(2047 - bi);
    key = red64_maxk(key);  // wave winner at lane 63
    const int par = it & 1;
    if ((t & 63) == 63) {
      const int widx = 2047 - (int)((unsigned)key & 2047u);
      skey[par][t >> 6] = key;
      scoord[par][t >> 6] = make_float4(xs[widx], ys[widx], zs[widx], 0.0f);
    }
    __syncthreads();
    unsigned long long k0 = skey[par][0], k1 = skey[par][1];
    unsigned long long k2 = skey[par][2], k3 = skey[par][3];
    float4 c0 = scoord[par][0], c1 = scoord[par][1];
    float4 c2 = scoord[par][2], c3 = scoord[par][3];
    if (k1 > k0) { k0 = k1; c0 = c1; }
    if (k3 > k2) { k2 = k3; c2 = c3; }
    if (k2 > k0) { k0 = k2; c0 = c2; }
    far = 2047 - (int)((unsigned)k0 & 2047u);
    cx = c0.x; cy = c0.y; cz = c0.z;
  }
}

// ---------------------------------------------------------------------------
// K2: ball query. One wave per centroid. Writes the first-32 ascending
// in-radius indices to gidx[g*32 + pos] and the DISTINCT count to gn[g]
// (no padding: max over duplicates == max over distinct, so downstream only
// needs the distinct prefix). Every group has >= 1 hit (its own centroid).
// ---------------------------------------------------------------------------
__global__ __launch_bounds__(256) void k_ballq(const float* __restrict__ xyz,
                                               const int* __restrict__ fidx,
                                               float* __restrict__ new_xyz,
                                               int* __restrict__ gidx,
                                               int* __restrict__ gn) {
  const int gw = (blockIdx.x * 256 + threadIdx.x) >> 6;  // centroid id
  const int lane = threadIdx.x & 63;
  const int b = gw >> 9;
  const float* P = xyz + (size_t)b * 6144;
  const int cidx = fidx[gw];
  const float cx = P[3 * cidx], cy = P[3 * cidx + 1], cz = P[3 * cidx + 2];
  if (lane < 3) new_xyz[(size_t)gw * 3 + lane] = P[3 * cidx + lane];
  int* g = gidx + (size_t)gw * 32;
  int base = 0;
  for (int c0 = 0; c0 < 2048; c0 += 64) {
    const int idx = c0 + lane;
    const float d = sq3(cx, cy, cz, P[3 * idx], P[3 * idx + 1], P[3 * idx + 2]);
    const bool in = !(d > 0.04f);  // matches: exclude where sqr > r*r
    const unsigned long long m = __ballot(in);
    if (in) {
      const int pos = base + (int)__popcll(m & ((1ull << lane) - 1ull));
      if (pos < 32) g[pos] = idx;
    }
    base += (int)__popcll(m);
    if (base >= 32) break;  // wave-uniform
  }
  if (lane == 0) gn[gw] = (base < 32) ? base : 32;
}

// ---------------------------------------------------------------------------
// K3: SA1, one WAVE per group, items looped (E[n] ~ 2-3 of max 32; round-10
// showed the padded-duplicate evaluations were ~90% of sa1's work, and its
// atomicMax combine cost 113 MB of device-scope RMW traffic -> 364 us).
// Register-only reduction: lane d computes h0[d]; cross-lane broadcast via
// v_readlane (compile-time lane index, scalar-operand FMA -> no LDS, no
// barriers); lane owns sv[lane] and outputs {lane, lane+64}, max-accumulated
// in 2 VGPRs. Per-wave one-time weight preload: w1 row + 2 w2 rows = 192
// VGPRs (launch_bounds(256,2) -> 256 cap). All values >= 0; acc init 0 is
// identity. 4 waves/block (independent groups, no block barriers), grid 4096.
// ---------------------------------------------------------------------------
__global__ __launch_bounds__(256, 2) void k_sa1g(
    const float* __restrict__ xyz, const float* __restrict__ new_xyz,
    const int* __restrict__ gidx, const int* __restrict__ gn,
    const float* __restrict__ w0, const float* __restrict__ b0,
    const float* __restrict__ w1, const float* __restrict__ b1,
    const float* __restrict__ w2, const float* __restrict__ b2,
    float* __restrict__ l1p) {
  const int wv = threadIdx.x >> 6, lane = threadIdx.x & 63;
  const int g = blockIdx.x * 4 + wv;  // group id
  const int b = g >> 9;
  // per-wave weight preload (one-time; L1/L2-hot after first block)
  float w1r[64], w2ra[64], w2rb[64];
#pragma unroll
  for (int c = 0; c < 64; ++c) w1r[c] = w1[(lane << 6) + c];
#pragma unroll
  for (int c = 0; c < 64; ++c) w2ra[c] = w2[(lane << 6) + c];
#pragma unroll
  for (int c = 0; c < 64; ++c) w2rb[c] = w2[((lane + 64) << 6) + c];
  const float w0x = w0[3 * lane], w0y = w0[3 * lane + 1], w0z = w0[3 * lane + 2];
  const float b0l = b0[lane], b1l = b1[lane];
  const float b2a = b2[lane], b2b = b2[lane + 64];
  const float* P = xyz + (size_t)b * 6144;
  const float nx = new_xyz[(size_t)g * 3], ny = new_xyz[(size_t)g * 3 + 1],
              nz = new_xyz[(size_t)g * 3 + 2];
  const int n = gn[g];  // wave-uniform
  const int* items = gidx + (size_t)g * 32;
  float acca = 0.0f, accb = 0.0f;  // relu outputs >= 0 -> 0 is max-identity
  for (int i = 0; i < n; ++i) {
    const int src = items[i];  // wave-uniform
    const float x = P[3 * src] - nx, y = P[3 * src + 1] - ny,
                z = P[3 * src + 2] - nz;
    // layer 0: lane owns dim `lane`
    const float h = fmaxf(0.0f, fmaf(w0x, x, fmaf(w0y, y, fmaf(w0z, z, b0l))));
    // layer 1: sv[lane] = relu(b1 + sum_c w1[lane][c] * h0[c]) via readlane
    float s0 = 0.f, s1 = 0.f, s2 = 0.f, s3 = 0.f;
#pragma unroll
    for (int c = 0; c < 64; c += 4) {
      s0 = fmaf(w1r[c], rdlane(h, c), s0);
      s1 = fmaf(w1r[c + 1], rdlane(h, c + 1), s1);
      s2 = fmaf(w1r[c + 2], rdlane(h, c + 2), s2);
      s3 = fmaf(w1r[c + 3], rdlane(h, c + 3), s3);
    }
    const float sv = fmaxf(0.0f, b1l + ((s0 + s1) + (s2 + s3)));
    // layer 2: lane owns outputs lane and lane+64
    float a0 = 0.f, a1 = 0.f, a2 = 0.f, a3 = 0.f;
    float u0 = 0.f, u1 = 0.f, u2 = 0.f, u3 = 0.f;
#pragma unroll
    for (int c = 0; c < 64; c += 4) {
      const float v0 = rdlane(sv, c), v1 = rdlane(sv, c + 1);
      const float v2 = rdlane(sv, c + 2), v3 = rdlane(sv, c + 3);
      a0 = fmaf(w2ra[c], v0, a0);
      a1 = fmaf(w2ra[c + 1], v1, a1);
      a2 = fmaf(w2ra[c + 2], v2, a2);
      a3 = fmaf(w2ra[c + 3], v3, a3);
      u0 = fmaf(w2rb[c], v0, u0);
      u1 = fmaf(w2rb[c + 1], v1, u1);
      u2 = fmaf(w2rb[c + 2], v2, u2);
      u3 = fmaf(w2rb[c + 3], v3, u3);
    }
    acca = fmaxf(acca, fmaxf(0.0f, b2a + ((a0 + a1) + (a2 + a3))));
    accb = fmaxf(accb, fmaxf(0.0f, b2b + ((u0 + u1) + (u2 + u3))));
  }
  float* outg = l1p + (size_t)g * 128;
  outg[lane] = acca;
  outg[lane + 64] = accb;
}

// ---------------------------------------------------------------------------
// SA2 layer kernels: lane = point (m), A row in registers (float4 packed
// [d/4][m][4] intermediates), weights via wave-uniform scalar path.
// 16-dim chunks for 2-4 blocks/CU latency hiding (round-6 win).
// ---------------------------------------------------------------------------
__global__ __launch_bounds__(256, 2) void k_sa2_l0(
    const float* __restrict__ new_xyz, const float* __restrict__ l1p,
    const float* __restrict__ w0, const float* __restrict__ b0,
    float4* __restrict__ h0t4) {
  const int pb = blockIdx.x >> 3, ds = blockIdx.x & 7;  // 8 chunks x 16 dims
  const int t = threadIdx.x;
  const int d0 = ds * 16;
  const int m = pb * 256 + t;
  const float ax = new_xyz[(size_t)m * 3], ay = new_xyz[(size_t)m * 3 + 1],
              az = new_xyz[(size_t)m * 3 + 2];
  float4 av[32];
  const float4* lp = (const float4*)(l1p + (size_t)m * 128);
#pragma unroll
  for (int i = 0; i < 32; ++i) av[i] = lp[i];
  for (int dq = 0; dq < 4; ++dq) {
    float o[4];
#pragma unroll
    for (int k = 0; k < 4; ++k) {
      const int dd = 4 * dq + k;
      const float* wr = w0 + (size_t)(d0 + dd) * 131;
      float s = fmaf(wr[0], ax, fmaf(wr[1], ay, fmaf(wr[2], az, b0[d0 + dd])));
      float s0 = 0.f, s1 = 0.f, s2 = 0.f, s3 = 0.f;
#pragma unroll
      for (int i = 0; i < 32; ++i) {
        s0 = fmaf(wr[3 + 4 * i], av[i].x, s0);
        s1 = fmaf(wr[4 + 4 * i], av[i].y, s1);
        s2 = fmaf(wr[5 + 4 * i], av[i].z, s2);
        s3 = fmaf(wr[6 + 4 * i], av[i].w, s3);
      }
      o[k] = fmaxf(0.0f, s + ((s0 + s1) + (s2 + s3)));
    }
    h0t4[(size_t)(ds * 4 + dq) * 16384 + m] =
        make_float4(o[0], o[1], o[2], o[3]);
  }
}

__global__ __launch_bounds__(256, 2) void k_sa2_l1(
    const float4* __restrict__ h0t4, const float* __restrict__ w1,
    const float* __restrict__ b1, float4* __restrict__ h1t4) {
  const int pb = blockIdx.x >> 3, ds = blockIdx.x & 7;  // 8 chunks x 16 dims
  const int t = threadIdx.x;
  const int d0 = ds * 16;
  const int m = pb * 256 + t;
  float4 a4[32];
#pragma unroll
  for (int i = 0; i < 32; ++i) a4[i] = h0t4[(size_t)i * 16384 + m];
  for (int dq = 0; dq < 4; ++dq) {
    float o[4];
#pragma unroll
    for (int k = 0; k < 4; ++k) {
      const int dd = 4 * dq + k;
      const float* wr = w1 + (size_t)(d0 + dd) * 128;
      float s0 = 0.f, s1 = 0.f, s2 = 0.f, s3 = 0.f;
#pragma unroll
      for (int i = 0; i < 32; ++i) {
        s0 = fmaf(wr[4 * i], a4[i].x, s0);
        s1 = fmaf(wr[4 * i + 1], a4[i].y, s1);
        s2 = fmaf(wr[4 * i + 2], a4[i].z, s2);
        s3 = fmaf(wr[4 * i + 3], a4[i].w, s3);
      }
      o[k] = fmaxf(0.0f, b1[d0 + dd] + ((s0 + s1) + (s2 + s3)));
    }
    h1t4[(size_t)(ds * 4 + dq) * 16384 + m] =
        make_float4(o[0], o[1], o[2], o[3]);
  }
}

__global__ __launch_bounds__(256, 2) void k_sa2_l2max(
    const float4* __restrict__ h1t4, const float* __restrict__ w2,
    const float* __restrict__ b2, float* __restrict__ pmax) {
  const int pb = blockIdx.x >> 4, ds = blockIdx.x & 15;  // 16 chunks x 16 dims
  const int t = threadIdx.x;
  const int d0 = ds * 16;
  const int m = pb * 256 + t;
  const int b = m >> 9;
  const int wc = ((pb << 2) + (t >> 6)) & 7;  // wave-chunk within batch (0..7)
  float4 a4[32];
#pragma unroll
  for (int i = 0; i < 32; ++i) a4[i] = h1t4[(size_t)i * 16384 + m];
  for (int dq = 0; dq < 4; ++dq) {
#pragma unroll
    for (int k = 0; k < 4; ++k) {
      const int dd = 4 * dq + k;
      const float* wr = w2 + (size_t)(d0 + dd) * 128;
      float s0 = 0.f, s1 = 0.f, s2 = 0.f, s3 = 0.f;
#pragma unroll
      for (int i = 0; i < 32; ++i) {
        s0 = fmaf(wr[4 * i], a4[i].x, s0);
        s1 = fmaf(wr[4 * i + 1], a4[i].y, s1);
        s2 = fmaf(wr[4 * i + 2], a4[i].z, s2);
        s3 = fmaf(wr[4 * i + 3], a4[i].w, s3);
      }
      float v = fmaxf(0.0f, b2[d0 + dd] + ((s0 + s1) + (s2 + s3)));
      v = red64_maxf(v);  // wave max, valid at lane 63
      if ((t & 63) == 63) pmax[((size_t)(b << 3) + wc) * 256 + d0 + dd] = v;
    }
  }
}

// ---------------------------------------------------------------------------
// K7: head. One block (1 wave) per batch. obj = max over 8 wave-partials,
// pose MLP + fusion MLP + two scalar heads.
// ---------------------------------------------------------------------------
__global__ __launch_bounds__(64) void k_head(
    const float* __restrict__ pmax, const float* __restrict__ grasp,
    const float* __restrict__ initp, const float* __restrict__ finalp,
    const int* __restrict__ surf, const float* __restrict__ embi,
    const float* __restrict__ embf, const float* __restrict__ pw0,
    const float* __restrict__ pb0, const float* __restrict__ pw1,
    const float* __restrict__ pb1, const float* __restrict__ pw2,
    const float* __restrict__ pb2, const float* __restrict__ fw0,
    const float* __restrict__ fb0, const float* __restrict__ fw1,
    const float* __restrict__ fb1, const float* __restrict__ osw,
    const float* __restrict__ osb, const float* __restrict__ ocw,
    const float* __restrict__ ocb, float* __restrict__ out) {
  __shared__ float obj[256], xb[37], A0[64], A1[128], A2[128], F0[128], HID[64];
  const int b = blockIdx.x, l = threadIdx.x;
  const float* pm = pmax + (size_t)b * 2048;
  for (int e = l; e < 256; e += 64) {
    float v = pm[e];
#pragma unroll
    for (int w = 1; w < 8; ++w) v = fmaxf(v, pm[w * 256 + e]);
    obj[e] = v;
  }
  if (l < 7) xb[l] = grasp[b * 7 + l];
  else if (l < 14) xb[l] = initp[b * 7 + l - 7];
  else if (l < 21) xb[l] = finalp[b * 7 + l - 14];
  else if (l < 29) xb[l] = embi[surf[b * 2] * 8 + l - 21];
  else if (l < 37) xb[l] = embf[surf[b * 2 + 1] * 8 + l - 29];
  __syncthreads();
  {
    float s = pb0[l];
    const float* wr = pw0 + l * 37;
#pragma unroll
    for (int c = 0; c < 37; ++c) s = fmaf(xb[c], wr[c], s);
    A0[l] = fmaxf(0.f, s);
  }
  __syncthreads();
#pragma unroll
  for (int dd = 0; dd < 2; ++dd) {
    const int d = l + dd * 64;
    float s = pb1[d];
    const float* wr = pw1 + d * 64;
#pragma unroll
    for (int c = 0; c < 64; ++c) s = fmaf(A0[c], wr[c], s);
    A1[d] = fmaxf(0.f, s);
  }
  __syncthreads();
#pragma unroll
  for (int dd = 0; dd < 2; ++dd) {
    const int d = l + dd * 64;
    float s = pb2[d];
    const float* wr = pw2 + d * 128;
#pragma unroll 16
    for (int c = 0; c < 128; ++c) s = fmaf(A1[c], wr[c], s);
    A2[d] = fmaxf(0.f, s);
  }
  __syncthreads();
#pragma unroll
  for (int dd = 0; dd < 2; ++dd) {
    const int d = l + dd * 64;
    float s = fb0[d];
    const float* wr = fw0 + d * 384;
#pragma unroll 16
    for (int c = 0; c < 256; ++c) s = fmaf(obj[c], wr[c], s);
#pragma unroll 16
    for (int c = 0; c < 128; ++c) s = fmaf(A2[c], wr[256 + c], s);
    F0[d] = fmaxf(0.f, s);
  }
  __syncthreads();
  {
    float s = fb1[l];
    const float* wr = fw1 + l * 128;
#pragma unroll 16
    for (int c = 0; c < 128; ++c) s = fmaf(F0[c], wr[c], s);
    HID[l] = fmaxf(0.f, s);
  }
  __syncthreads();
  float v1 = HID[l] * osw[l];
  float v2 = HID[l] * ocw[l];
#pragma unroll
  for (int off = 1; off < 64; off <<= 1) {
    v1 += __shfl_xor(v1, off);
    v2 += __shfl_xor(v2, off);
  }
  if (l == 0) {
    out[b] = v1 + osb[0];
    out[32 + b] = v2 + ocb[0];
  }
}

extern "C" void kernel_launch(void* const* d_in, const int* in_sizes, int n_in,
                              void* d_out, int out_size, void* d_ws, size_t ws_size,
                              hipStream_t stream) {
  const float* points  = (const float*)d_in[0];
  const float* grasp   = (const float*)d_in[1];
  const float* initp   = (const float*)d_in[2];
  const float* finalp  = (const float*)d_in[3];
  const int*   surf    = (const int*)d_in[4];
  const float* sa1_w0  = (const float*)d_in[5];
  const float* sa1_b0  = (const float*)d_in[6];
  const float* sa1_w1  = (const float*)d_in[7];
  const float* sa1_b1  = (const float*)d_in[8];
  const float* sa1_w2  = (const float*)d_in[9];
  const float* sa1_b2  = (const float*)d_in[10];
  const float* sa2_w0  = (const float*)d_in[11];
  const float* sa2_b0  = (const float*)d_in[12];
  const float* sa2_w1  = (const float*)d_in[13];
  const float* sa2_b1  = (const float*)d_in[14];
  const float* sa2_w2  = (const float*)d_in[15];
  const float* sa2_b2  = (const float*)d_in[16];
  const float* embi    = (const float*)d_in[17];
  const float* embf    = (const float*)d_in[18];
  const float* pe_w0   = (const float*)d_in[19];
  const float* pe_b0   = (const float*)d_in[20];
  const float* pe_w1   = (const float*)d_in[21];
  const float* pe_b1   = (const float*)d_in[22];
  const float* pe_w2   = (const float*)d_in[23];
  const float* pe_b2   = (const float*)d_in[24];
  const float* fu_w0   = (const float*)d_in[25];
  const float* fu_b0   = (const float*)d_in[26];
  const float* fu_w1   = (const float*)d_in[27];
  const float* fu_b1   = (const float*)d_in[28];
  const float* os_w    = (const float*)d_in[29];
  const float* os_b    = (const float*)d_in[30];
  const float* oc_w    = (const float*)d_in[31];
  const float* oc_b    = (const float*)d_in[32];

  char* ws = (char*)d_ws;
  // layout (bytes):
  int*    fidx    = (int*)(ws + 0);               //  65536
  float*  new_xyz = (float*)(ws + 65536);         // 196608
  int*    gidx    = (int*)(ws + 262144);          // 2097152 (16384*32*4)
  float*  l1p     = (float*)(ws + 2359296);       // 8388608 (reused as h1t)
  float4* h0t4    = (float4*)(ws + 10747904);     // 8388608
  float*  pmax    = (float*)(ws + 19136512);      // 262144
  int*    gn      = (int*)(ws + 19398656);        // 65536 -> end 19464192
  float4* h1t4    = (float4*)l1p;  // l1_points dead after k_sa2_l0

  float* out = (float*)d_out;

  k_fps<<<32, 256, 0, stream>>>(points, fidx);
  k_ballq<<<4096, 256, 0, stream>>>(points, fidx, new_xyz, gidx, gn);
  k_sa1g<<<4096, 256, 0, stream>>>(points, new_xyz, gidx, gn, sa1_w0, sa1_b0,
                                   sa1_w1, sa1_b1, sa1_w2, sa1_b2, l1p);
  k_sa2_l0<<<512, 256, 0, stream>>>(new_xyz, l1p, sa2_w0, sa2_b0, h0t4);
  k_sa2_l1<<<512, 256, 0, stream>>>(h0t4, sa2_w1, sa2_b1, h1t4);
  k_sa2_l2max<<<1024, 256, 0, stream>>>(h1t4, sa2_w2, sa2_b2, pmax);
  k_head<<<32, 64, 0, stream>>>(pmax, grasp, initp, finalp, surf, embi, embf,
                                pe_w0, pe_b0, pe_w1, pe_b1, pe_w2, pe_b2, fu_w0,
                                fu_b0, fu_w1, fu_b1, os_w, os_b, oc_w, oc_b, out);
}